// Round 11
// baseline (217.559 us; speedup 1.0000x reference)
//
#include <hip/hip_runtime.h>

typedef unsigned short u16;
typedef unsigned int u32;
typedef __attribute__((ext_vector_type(8))) u16 u16x8;
typedef __attribute__((ext_vector_type(8))) __bf16 bf16x8;
typedef __attribute__((ext_vector_type(4))) float f32x4;

#define LOG2E_F 1.4426950408889634f

__device__ __forceinline__ u16 f2bf(float f) {
  return (u16)(__float_as_uint(f) >> 16);
}
__device__ __forceinline__ float clip87(float x) {
  return fminf(fmaxf(x, -8.0f), 7.0f);
}

// async global->LDS, 16B per lane; lptr must be wave-uniform (HW: lptr + lane*16)
typedef const __attribute__((address_space(1))) u32* gp32;
typedef __attribute__((address_space(3))) u32* lp32;
__device__ __forceinline__ void gl16(const void* g, void* l) {
  __builtin_amdgcn_global_load_lds((gp32)g, (lp32)l, 16, 0, 0);
}

// ---------------- scalar means + derived constants ----------------
// scal: [0]=a_in [1]=aq [2]=ak [3]=av [4]=am [5]=ap [6]=escale [7]=am*av
__global__ void k_scalars(const float* __restrict__ qkv_act_alpha,
                          const float* __restrict__ proj_act_alpha,
                          const float* __restrict__ q_alpha,
                          const float* __restrict__ k_alpha,
                          const float* __restrict__ v_alpha,
                          const float* __restrict__ attn_alpha,
                          float* __restrict__ scal) {
  int tid = threadIdx.x;
  int wave = tid >> 6, lane = tid & 63;
  if (wave < 6) {
    const float* src = nullptr; int n = 0;
    switch (wave) {
      case 0: src = qkv_act_alpha;  n = 768; break;
      case 1: src = q_alpha;        n = 12;  break;
      case 2: src = k_alpha;        n = 12;  break;
      case 3: src = v_alpha;        n = 12;  break;
      case 4: src = attn_alpha;     n = 12;  break;
      case 5: src = proj_act_alpha; n = 768; break;
    }
    double s = 0.0;
    for (int i = lane; i < n; i += 64) s += (double)src[i];
    s += __shfl_xor(s, 1);
    s += __shfl_xor(s, 2);
    s += __shfl_xor(s, 4);
    s += __shfl_xor(s, 8);
    s += __shfl_xor(s, 16);
    s += __shfl_xor(s, 32);
    if (lane == 0) scal[wave] = (float)(s / (double)n);
  }
  __syncthreads();
  if (tid == 0) {
    float aq = scal[1], ak = scal[2];
    float s_ = (0.125f * aq) * ak;   // head_scale * aq * ak
    scal[6] = LOG2E_F * s_;          // escale
    scal[7] = scal[4] * scal[3];     // am * av
  }
}

// ---------------- weight quantization ----------------
__global__ __launch_bounds__(256) void k_quant_weights(
    const float* __restrict__ qkv_w, const float* __restrict__ qkv_alpha,
    const float* __restrict__ qkv_b, const float* __restrict__ proj_w,
    const float* __restrict__ proj_alpha, const float* __restrict__ scal,
    u16* __restrict__ wq, u16* __restrict__ wp, float* __restrict__ biasi) {
  int idx = blockIdx.x * 256 + threadIdx.x;
  const int T1 = 2304 * 768, T2 = 768 * 768;
  if (idx < T1) {
    int o = idx / 768;
    wq[idx] = f2bf(rintf(clip87(qkv_w[idx] / qkv_alpha[o])));
  } else if (idx < T1 + T2) {
    int j = idx - T1;
    int o = j / 768;
    wp[j] = f2bf(rintf(clip87(proj_w[j] / proj_alpha[o])));
  } else if (idx < T1 + T2 + 2304) {
    int o = idx - T1 - T2;
    biasi[o] = truncf((qkv_b[o] / scal[0]) / qkv_alpha[o]);
  }
}

// ---------------- x0 activation quantization ----------------
__global__ __launch_bounds__(256) void k_quant_x0(const float* __restrict__ x0,
                                                  const float* __restrict__ scal,
                                                  u16* __restrict__ x0q) {
  int base = (blockIdx.x * 256 + threadIdx.x) * 8;
  float a = scal[0];
  f32x4 v0 = *(const f32x4*)&x0[base];
  f32x4 v1 = *(const f32x4*)&x0[base + 4];
  u16x8 o;
  #pragma unroll
  for (int j = 0; j < 4; j++) o[j] = f2bf(rintf(clip87(v0[j] / a)));
  #pragma unroll
  for (int j = 0; j < 4; j++) o[4 + j] = f2bf(rintf(clip87(v1[j] / a)));
  *(u16x8*)&x0q[base] = o;
}

// ================= 64x64 GEMM core =================
// BK=64, double-buffered LDS (32KB total), XOR-swizzled staging.
// Wave w stages rows w*16..w*16+15 of each tile (2 gl16 issues per matrix).
// Lane l: row-sub l>>3, stored block l&7, src block (l&7)^(l>>3).
// Read: block j of row r is stored at j^(r&7).
#define BUF_A64(c) (smem_u16 + (c) * 4096)
#define BUF_B64(c) (smem_u16 + 8192 + (c) * 4096)

__device__ __forceinline__ void stage64(const u16* gAl, const u16* gBl, int K,
                                        u16* bufA, u16* bufB, int w) {
  gl16(gAl, bufA + (w * 16) * 64);
  gl16(gAl + (size_t)8 * K, bufA + (w * 16 + 8) * 64);
  gl16(gBl, bufB + (w * 16) * 64);
  gl16(gBl + (size_t)8 * K, bufB + (w * 16 + 8) * 64);
}

__device__ __forceinline__ void gemm64(const u16* __restrict__ A,
                                       const u16* __restrict__ Bt, int K,
                                       int m0, int n0, u16* smem_u16,
                                       int lane, int wave, f32x4 acc[2][2]) {
  int rsub = lane >> 3;
  int jsrc = (lane & 7) ^ rsub;
  const u16* gAl = A + (size_t)(m0 + wave * 16 + rsub) * K + jsrc * 8;
  const u16* gBl = Bt + (size_t)(n0 + wave * 16 + rsub) * K + jsrc * 8;

  int arow = (wave >> 1) * 32 + (lane & 15);
  int brow = (wave & 1) * 32 + (lane & 15);
  int nsteps = K / 64;

  stage64(gAl, gBl, K, BUF_A64(0), BUF_B64(0), wave);
  __syncthreads();
  for (int t = 0; t < nsteps; t++) {
    int cur = t & 1;
    if (t + 1 < nsteps)
      stage64(gAl + (t + 1) * 64, gBl + (t + 1) * 64, K,
              BUF_A64(cur ^ 1), BUF_B64(cur ^ 1), wave);
    const u16* bA = BUF_A64(cur);
    const u16* bB = BUF_B64(cur);
    #pragma unroll
    for (int kk = 0; kk < 2; kk++) {
      int jj = ((kk * 4 + (lane >> 4)) ^ (lane & 7)) * 8;
      bf16x8 af0 = *(const bf16x8*)&bA[arow * 64 + jj];
      bf16x8 af1 = *(const bf16x8*)&bA[(arow + 16) * 64 + jj];
      bf16x8 bf0 = *(const bf16x8*)&bB[brow * 64 + jj];
      bf16x8 bf1 = *(const bf16x8*)&bB[(brow + 16) * 64 + jj];
      acc[0][0] = __builtin_amdgcn_mfma_f32_16x16x32_bf16(af0, bf0, acc[0][0], 0, 0, 0);
      acc[0][1] = __builtin_amdgcn_mfma_f32_16x16x32_bf16(af0, bf1, acc[0][1], 0, 0, 0);
      acc[1][0] = __builtin_amdgcn_mfma_f32_16x16x32_bf16(af1, bf0, acc[1][0], 0, 0, 0);
      acc[1][1] = __builtin_amdgcn_mfma_f32_16x16x32_bf16(af1, bf1, acc[1][1], 0, 0, 0);
    }
    __syncthreads();
  }
}

// ---------------- qkv GEMM with FUSED branch quantization ----------------
// grid (36, 64): bx -> branch = bx/12 (0=q,1=k,2=v), head h = bx%12; m0 = by*64.
__global__ __launch_bounds__(256) void k_gemm_qkv(
    const u16* __restrict__ A, const u16* __restrict__ Bt,
    const float* __restrict__ biasi, const float* __restrict__ qkv_alpha,
    const float* __restrict__ nqw, const float* __restrict__ nqb,
    const float* __restrict__ nkw, const float* __restrict__ nkb,
    const float* __restrict__ scal,
    u16* __restrict__ q2, u16* __restrict__ k2, u16* __restrict__ v2t) {
  const int K = 768;
  __shared__ __align__(16) char smem[32768];   // staging 32KB; xt 64*65*4=16.6KB
  u16* smem_u16 = (u16*)smem;
  float* xt = (float*)smem;
  int tid = threadIdx.x;
  int lane = tid & 63, wave = tid >> 6;
  int wr = wave >> 1, wc = wave & 1;
  int m0 = blockIdx.y * 64, n0 = blockIdx.x * 64;

  f32x4 acc[2][2];
  #pragma unroll
  for (int mi = 0; mi < 2; mi++)
    #pragma unroll
    for (int ni = 0; ni < 2; ni++) acc[mi][ni] = (f32x4){0.f, 0.f, 0.f, 0.f};

  gemm64(A, Bt, K, m0, n0, smem_u16, lane, wave, acc);
  // final barrier of gemm64: safe to repurpose smem as xt

  // ---- phase 1: raw qkv tile (acc + bias) -> LDS [64][65] ----
  int lrow = (lane >> 4) * 4, lcol = lane & 15;
  #pragma unroll
  for (int mi = 0; mi < 2; mi++)
    #pragma unroll
    for (int ni = 0; ni < 2; ni++) {
      int c = wc * 32 + ni * 16 + lcol;
      float bs = biasi[n0 + c];
      #pragma unroll
      for (int rr = 0; rr < 4; rr++) {
        int r = wr * 32 + mi * 16 + lrow + rr;
        xt[r * 65 + c] = acc[mi][ni][rr] + bs;
      }
    }
  __syncthreads();

  // ---- phase 2: branch quantization ----
  int branch = blockIdx.x / 12, h = blockIdx.x % 12;
  int b = m0 >> 10, nb = m0 & 1023;
  if (branch == 2) {
    // v: thread owns (d = tid&63, row-quarter qr = tid>>6); transpose-write
    int d = tid & 63, qr = tid >> 6;
    float av = scal[3];
    float coefv = scal[0] * qkv_alpha[1536 + h * 64 + d];
    u16* dst = v2t + ((size_t)(b * 12 + h) * 64 + d) * 1024 + nb + qr * 16;
    #pragma unroll
    for (int g = 0; g < 2; g++) {
      u16x8 t8;
      #pragma unroll
      for (int j = 0; j < 8; j++) {
        float val = xt[(qr * 16 + g * 8 + j) * 65 + d];
        t8[j] = f2bf(rintf(clip87((val * coefv) / av)));
      }
      *(u16x8*)(dst + g * 8) = t8;
    }
  } else if (tid < 64) {
    // q/k: lane owns one row; serial int mean/var recurrence (64 rows in parallel)
    int r = tid;
    const float* alph = qkv_alpha + branch * 768 + h * 64;
    const float* wv = branch == 0 ? nqw : nkw;
    const float* bv = branch == 0 ? nqb : nkb;
    float as = branch == 0 ? scal[1] : scal[2];
    float xq[64];
    #pragma unroll
    for (int d = 0; d < 64; d++) xq[d] = xt[r * 65 + d] * alph[d];
    int m = 0, v = 0;
    #pragma unroll
    for (int i = 0; i < 64; i++) {
      int xi = (int)xq[i];
      int dd = xi - m;
      m += (dd * (1024 / (i + 1))) >> 10;   // floor div by 1024
      v += dd * (xi - m);
    }
    float muf = (float)m;
    float den = sqrtf((float)v * 0.015625f) + 1e-5f;
    u16* outp = (branch == 0 ? q2 : k2) + ((size_t)(b * 12 + h) * 1024 + nb + r) * 64;
    #pragma unroll
    for (int g = 0; g < 8; g++) {
      u16x8 t8;
      #pragma unroll
      for (int j = 0; j < 8; j++) {
        int d = g * 8 + j;
        float q1 = (xq[d] - muf) / den;
        float bw = bv[d] / wv[d];
        float t = (q1 + bw) * wv[d] / as;
        t8[j] = f2bf(rintf(clip87(t)));
      }
      *(u16x8*)(outp + g * 8) = t8;
    }
  }
}

// ---------------- proj GEMM: C = A * B^T, fused scale+bias epilogue ----------------
// grid (12, 64): 64x64 tiles.
__global__ __launch_bounds__(256) void k_gemm_proj(
    const u16* __restrict__ A, const u16* __restrict__ Bt,
    float* __restrict__ Cout, const float* __restrict__ palpha,
    const float* __restrict__ pbias, const float* __restrict__ scal) {
  const int K = 768, N = 768;
  __shared__ __align__(16) char smem[32768];
  u16* smem_u16 = (u16*)smem;
  int tid = threadIdx.x;
  int lane = tid & 63, wave = tid >> 6;
  int wr = wave >> 1, wc = wave & 1;
  int m0 = blockIdx.y * 64, n0 = blockIdx.x * 64;

  f32x4 acc[2][2];
  #pragma unroll
  for (int mi = 0; mi < 2; mi++)
    #pragma unroll
    for (int ni = 0; ni < 2; ni++) acc[mi][ni] = (f32x4){0.f, 0.f, 0.f, 0.f};

  gemm64(A, Bt, K, m0, n0, smem_u16, lane, wave, acc);

  int lrow = (lane >> 4) * 4, lcol = lane & 15;
  float ap = scal[5];
  #pragma unroll
  for (int mi = 0; mi < 2; mi++)
    #pragma unroll
    for (int ni = 0; ni < 2; ni++) {
      int col = n0 + wc * 32 + ni * 16 + lcol;
      float pa = palpha[col], pb = pbias[col];
      #pragma unroll
      for (int rr = 0; rr < 4; rr++) {
        int row = m0 + wr * 32 + mi * 16 + lrow + rr;
        Cout[(size_t)row * N + col] = (acc[mi][ni][rr] * pa) * ap + pb;
      }
    }
}

// ---------------- fused attention ----------------
// grid (16, 48): qt = bx (64 q rows), bh = by. 4 waves; wave w owns q rows w*16..w*16+15.
__global__ __launch_bounds__(256) void k_attn(
    const u16* __restrict__ q2, const u16* __restrict__ k2,
    const u16* __restrict__ v2t, const float* __restrict__ scal,
    u16* __restrict__ x1q) {
  __shared__ __align__(16) u16 lK[64 * 72];
  __shared__ __align__(16) u16 lV[64 * 72];
  __shared__ __align__(16) u16 lP[64 * 72];
  __shared__ float rs_lds[64];
  int tid = threadIdx.x, lane = tid & 63, wave = tid >> 6;
  int qt = blockIdx.x, bh = blockIdx.y;
  const float escale = scal[6], am = scal[4], am_av = scal[7], apc = scal[5];

  size_t qrow = (size_t)bh * 1024 + qt * 64 + wave * 16 + (lane & 15);
  bf16x8 qf0 = *(const bf16x8*)(q2 + qrow * 64 + (lane >> 4) * 8);
  bf16x8 qf1 = *(const bf16x8*)(q2 + qrow * 64 + 32 + (lane >> 4) * 8);

  const u16* k2b = k2 + (size_t)bh * 1024 * 64;
  const u16* v2b = v2t + (size_t)bh * 64 * 1024;
  int sr = tid >> 2, sc = (tid & 3) * 16;

  // ---- pass 1: row sums of attn_exp (f32 per-kt partial, f64 across kt) ----
  double rsum[4] = {0.0, 0.0, 0.0, 0.0};
  for (int kt = 0; kt < 16; kt++) {
    const u16* src = k2b + (size_t)(kt * 64 + sr) * 64 + sc;
    *(u16x8*)&lK[sr * 72 + sc]     = *(const u16x8*)src;
    *(u16x8*)&lK[sr * 72 + sc + 8] = *(const u16x8*)(src + 8);
    __syncthreads();
    float part[4] = {0.f, 0.f, 0.f, 0.f};
    #pragma unroll
    for (int ct = 0; ct < 4; ct++) {
      bf16x8 kf0 = *(const bf16x8*)&lK[(ct * 16 + (lane & 15)) * 72 + (lane >> 4) * 8];
      bf16x8 kf1 = *(const bf16x8*)&lK[(ct * 16 + (lane & 15)) * 72 + 32 + (lane >> 4) * 8];
      f32x4 s = {0.f, 0.f, 0.f, 0.f};
      s = __builtin_amdgcn_mfma_f32_16x16x32_bf16(qf0, kf0, s, 0, 0, 0);
      s = __builtin_amdgcn_mfma_f32_16x16x32_bf16(qf1, kf1, s, 0, 0, 0);
      #pragma unroll
      for (int rr = 0; rr < 4; rr++) {
        float e = escale * s[rr];
        float f = floorf(e);
        float pe = ldexpf(1.0f + (e - f), (int)f);  // exact 2^f scaling
        part[rr] += pe;
      }
    }
    #pragma unroll
    for (int rr = 0; rr < 4; rr++) rsum[rr] += (double)part[rr];
    __syncthreads();
  }
  #pragma unroll
  for (int rr = 0; rr < 4; rr++) {
    double s = rsum[rr];
    s += __shfl_xor(s, 1);
    s += __shfl_xor(s, 2);
    s += __shfl_xor(s, 4);
    s += __shfl_xor(s, 8);
    if ((lane & 15) == 0) rs_lds[wave * 16 + (lane >> 4) * 4 + rr] = (float)s;
  }
  __syncthreads();
  float fac[4];
  #pragma unroll
  for (int rr = 0; rr < 4; rr++)
    fac[rr] = 1.0f / (rs_lds[wave * 16 + (lane >> 4) * 4 + rr] * am);

  // ---- pass 2: recompute S (bitwise identical), quantize attn, PV GEMM ----
  f32x4 accv[4];
  #pragma unroll
  for (int ct = 0; ct < 4; ct++) accv[ct] = (f32x4){0.f, 0.f, 0.f, 0.f};

  for (int kt = 0; kt < 16; kt++) {
    const u16* srcK = k2b + (size_t)(kt * 64 + sr) * 64 + sc;
    *(u16x8*)&lK[sr * 72 + sc]     = *(const u16x8*)srcK;
    *(u16x8*)&lK[sr * 72 + sc + 8] = *(const u16x8*)(srcK + 8);
    const u16* srcV = v2b + (size_t)sr * 1024 + kt * 64 + sc;
    *(u16x8*)&lV[sr * 72 + sc]     = *(const u16x8*)srcV;
    *(u16x8*)&lV[sr * 72 + sc + 8] = *(const u16x8*)(srcV + 8);
    __syncthreads();
    #pragma unroll
    for (int ct = 0; ct < 4; ct++) {
      bf16x8 kf0 = *(const bf16x8*)&lK[(ct * 16 + (lane & 15)) * 72 + (lane >> 4) * 8];
      bf16x8 kf1 = *(const bf16x8*)&lK[(ct * 16 + (lane & 15)) * 72 + 32 + (lane >> 4) * 8];
      f32x4 s = {0.f, 0.f, 0.f, 0.f};
      s = __builtin_amdgcn_mfma_f32_16x16x32_bf16(qf0, kf0, s, 0, 0, 0);
      s = __builtin_amdgcn_mfma_f32_16x16x32_bf16(qf1, kf1, s, 0, 0, 0);
      #pragma unroll
      for (int rr = 0; rr < 4; rr++) {
        float e = escale * s[rr];
        float f = floorf(e);
        float pe = ldexpf(1.0f + (e - f), (int)f);
        float a2 = rintf(fminf(pe * fac[rr], 7.0f));
        lP[(wave * 16 + (lane >> 4) * 4 + rr) * 72 + ct * 16 + (lane & 15)] = f2bf(a2);
      }
    }
    __syncthreads();
    bf16x8 pf0 = *(const bf16x8*)&lP[(wave * 16 + (lane & 15)) * 72 + (lane >> 4) * 8];
    bf16x8 pf1 = *(const bf16x8*)&lP[(wave * 16 + (lane & 15)) * 72 + 32 + (lane >> 4) * 8];
    #pragma unroll
    for (int ct = 0; ct < 4; ct++) {
      bf16x8 vf0 = *(const bf16x8*)&lV[(ct * 16 + (lane & 15)) * 72 + (lane >> 4) * 8];
      bf16x8 vf1 = *(const bf16x8*)&lV[(ct * 16 + (lane & 15)) * 72 + 32 + (lane >> 4) * 8];
      accv[ct] = __builtin_amdgcn_mfma_f32_16x16x32_bf16(pf0, vf0, accv[ct], 0, 0, 0);
      accv[ct] = __builtin_amdgcn_mfma_f32_16x16x32_bf16(pf1, vf1, accv[ct], 0, 0, 0);
    }
    __syncthreads();
  }

  int b = bh / 12, h = bh % 12;
  #pragma unroll
  for (int ct = 0; ct < 4; ct++)
    #pragma unroll
    for (int rr = 0; rr < 4; rr++) {
      int qr = qt * 64 + wave * 16 + (lane >> 4) * 4 + rr;
      int col = h * 64 + ct * 16 + (lane & 15);
      float t = (accv[ct][rr] * am_av) / apc;
      x1q[((size_t)b * 1024 + qr) * 768 + col] = f2bf(rintf(clip87(t)));
    }
}

extern "C" void kernel_launch(void* const* d_in, const int* in_sizes, int n_in,
                              void* d_out, int out_size, void* d_ws, size_t ws_size,
                              hipStream_t stream) {
  const float* x0             = (const float*)d_in[0];
  const float* qkv_w          = (const float*)d_in[1];
  const float* qkv_b          = (const float*)d_in[2];
  const float* qkv_alpha      = (const float*)d_in[3];
  const float* qkv_act_alpha  = (const float*)d_in[4];
  const float* proj_w         = (const float*)d_in[5];
  const float* proj_b         = (const float*)d_in[6];
  const float* proj_alpha     = (const float*)d_in[7];
  const float* proj_act_alpha = (const float*)d_in[8];
  const float* nqw            = (const float*)d_in[9];
  const float* nqb            = (const float*)d_in[10];
  const float* nkw            = (const float*)d_in[11];
  const float* nkb            = (const float*)d_in[12];
  const float* q_alpha        = (const float*)d_in[13];
  const float* k_alpha        = (const float*)d_in[14];
  const float* v_alpha        = (const float*)d_in[15];
  const float* attn_alpha     = (const float*)d_in[16];
  float* out = (float*)d_out;

  char* ws = (char*)d_ws;
  size_t off = 0;
  auto alloc = [&](size_t bytes) -> void* {
    off = (off + 255) & ~(size_t)255;
    void* p = ws + off;
    off += bytes;
    return p;
  };
  float* scal = (float*)alloc(64);
  u16* wq     = (u16*)alloc((size_t)2304 * 768 * 2);
  u16* wp     = (u16*)alloc((size_t)768 * 768 * 2);
  float* biasi= (float*)alloc((size_t)2304 * 4);
  u16* x0q    = (u16*)alloc((size_t)4096 * 768 * 2);
  u16* q2     = (u16*)alloc((size_t)48 * 1024 * 64 * 2);
  u16* k2     = (u16*)alloc((size_t)48 * 1024 * 64 * 2);
  u16* v2t    = (u16*)alloc((size_t)48 * 1024 * 64 * 2);
  u16* x1q    = (u16*)alloc((size_t)4096 * 768 * 2);

  k_scalars<<<1, 384, 0, stream>>>(qkv_act_alpha, proj_act_alpha, q_alpha, k_alpha,
                                   v_alpha, attn_alpha, scal);

  int totW = 2304 * 768 + 768 * 768 + 2304;
  k_quant_weights<<<(totW + 255) / 256, 256, 0, stream>>>(qkv_w, qkv_alpha, qkv_b,
                                                          proj_w, proj_alpha, scal,
                                                          wq, wp, biasi);

  k_quant_x0<<<(4096 * 768) / (256 * 8), 256, 0, stream>>>(x0, scal, x0q);

  k_gemm_qkv<<<dim3(36, 64), 256, 0, stream>>>(x0q, wq, biasi, qkv_alpha,
                                               nqw, nqb, nkw, nkb, scal,
                                               q2, k2, v2t);

  k_attn<<<dim3(16, 48), 256, 0, stream>>>(q2, k2, v2t, scal, x1q);

  k_gemm_proj<<<dim3(12, 64), 256, 0, stream>>>(x1q, wp, out, proj_alpha, proj_b, scal);
}

// Round 12
// 209.378 us; speedup vs baseline: 1.0391x; 1.0391x over previous
//
#include <hip/hip_runtime.h>

typedef unsigned short u16;
typedef unsigned int u32;
typedef __attribute__((ext_vector_type(8))) u16 u16x8;
typedef __attribute__((ext_vector_type(8))) __bf16 bf16x8;
typedef __attribute__((ext_vector_type(4))) float f32x4;

#define LOG2E_F 1.4426950408889634f

__device__ __forceinline__ u16 f2bf(float f) {
  return (u16)(__float_as_uint(f) >> 16);
}
__device__ __forceinline__ float clip87(float x) {
  return fminf(fmaxf(x, -8.0f), 7.0f);
}

// async global->LDS, 16B per lane; lptr must be wave-uniform (HW: lptr + lane*16)
typedef const __attribute__((address_space(1))) u32* gp32;
typedef __attribute__((address_space(3))) u32* lp32;
__device__ __forceinline__ void gl16(const void* g, void* l) {
  __builtin_amdgcn_global_load_lds((gp32)g, (lp32)l, 16, 0, 0);
}

// ---------------- scalar means + derived constants ----------------
// scal: [0]=a_in [1]=aq [2]=ak [3]=av [4]=am [5]=ap [6]=escale [7]=am*av
__global__ void k_scalars(const float* __restrict__ qkv_act_alpha,
                          const float* __restrict__ proj_act_alpha,
                          const float* __restrict__ q_alpha,
                          const float* __restrict__ k_alpha,
                          const float* __restrict__ v_alpha,
                          const float* __restrict__ attn_alpha,
                          float* __restrict__ scal) {
  int tid = threadIdx.x;
  int wave = tid >> 6, lane = tid & 63;
  if (wave < 6) {
    const float* src = nullptr; int n = 0;
    switch (wave) {
      case 0: src = qkv_act_alpha;  n = 768; break;
      case 1: src = q_alpha;        n = 12;  break;
      case 2: src = k_alpha;        n = 12;  break;
      case 3: src = v_alpha;        n = 12;  break;
      case 4: src = attn_alpha;     n = 12;  break;
      case 5: src = proj_act_alpha; n = 768; break;
    }
    double s = 0.0;
    for (int i = lane; i < n; i += 64) s += (double)src[i];
    s += __shfl_xor(s, 1);
    s += __shfl_xor(s, 2);
    s += __shfl_xor(s, 4);
    s += __shfl_xor(s, 8);
    s += __shfl_xor(s, 16);
    s += __shfl_xor(s, 32);
    if (lane == 0) scal[wave] = (float)(s / (double)n);
  }
  __syncthreads();
  if (tid == 0) {
    float aq = scal[1], ak = scal[2];
    float s_ = (0.125f * aq) * ak;   // head_scale * aq * ak
    scal[6] = LOG2E_F * s_;          // escale
    scal[7] = scal[4] * scal[3];     // am * av
  }
}

// ---------------- weight quantization ----------------
__global__ __launch_bounds__(256) void k_quant_weights(
    const float* __restrict__ qkv_w, const float* __restrict__ qkv_alpha,
    const float* __restrict__ qkv_b, const float* __restrict__ proj_w,
    const float* __restrict__ proj_alpha, const float* __restrict__ scal,
    u16* __restrict__ wq, u16* __restrict__ wp, float* __restrict__ biasi) {
  int idx = blockIdx.x * 256 + threadIdx.x;
  const int T1 = 2304 * 768, T2 = 768 * 768;
  if (idx < T1) {
    int o = idx / 768;
    wq[idx] = f2bf(rintf(clip87(qkv_w[idx] / qkv_alpha[o])));
  } else if (idx < T1 + T2) {
    int j = idx - T1;
    int o = j / 768;
    wp[j] = f2bf(rintf(clip87(proj_w[j] / proj_alpha[o])));
  } else if (idx < T1 + T2 + 2304) {
    int o = idx - T1 - T2;
    biasi[o] = truncf((qkv_b[o] / scal[0]) / qkv_alpha[o]);
  }
}

// ---------------- x0 activation quantization ----------------
__global__ __launch_bounds__(256) void k_quant_x0(const float* __restrict__ x0,
                                                  const float* __restrict__ scal,
                                                  u16* __restrict__ x0q) {
  int base = (blockIdx.x * 256 + threadIdx.x) * 8;
  float a = scal[0];
  f32x4 v0 = *(const f32x4*)&x0[base];
  f32x4 v1 = *(const f32x4*)&x0[base + 4];
  u16x8 o;
  #pragma unroll
  for (int j = 0; j < 4; j++) o[j] = f2bf(rintf(clip87(v0[j] / a)));
  #pragma unroll
  for (int j = 0; j < 4; j++) o[4 + j] = f2bf(rintf(clip87(v1[j] / a)));
  *(u16x8*)&x0q[base] = o;
}

// ================= 64x64 GEMM core =================
#define BUF_A64(c) (smem_u16 + (c) * 4096)
#define BUF_B64(c) (smem_u16 + 8192 + (c) * 4096)

__device__ __forceinline__ void stage64(const u16* gAl, const u16* gBl, int K,
                                        u16* bufA, u16* bufB, int w) {
  gl16(gAl, bufA + (w * 16) * 64);
  gl16(gAl + (size_t)8 * K, bufA + (w * 16 + 8) * 64);
  gl16(gBl, bufB + (w * 16) * 64);
  gl16(gBl + (size_t)8 * K, bufB + (w * 16 + 8) * 64);
}

__device__ __forceinline__ void gemm64(const u16* __restrict__ A,
                                       const u16* __restrict__ Bt, int K,
                                       int m0, int n0, u16* smem_u16,
                                       int lane, int wave, f32x4 acc[2][2]) {
  int rsub = lane >> 3;
  int jsrc = (lane & 7) ^ rsub;
  const u16* gAl = A + (size_t)(m0 + wave * 16 + rsub) * K + jsrc * 8;
  const u16* gBl = Bt + (size_t)(n0 + wave * 16 + rsub) * K + jsrc * 8;

  int arow = (wave >> 1) * 32 + (lane & 15);
  int brow = (wave & 1) * 32 + (lane & 15);
  int nsteps = K / 64;

  stage64(gAl, gBl, K, BUF_A64(0), BUF_B64(0), wave);
  __syncthreads();
  for (int t = 0; t < nsteps; t++) {
    int cur = t & 1;
    if (t + 1 < nsteps)
      stage64(gAl + (t + 1) * 64, gBl + (t + 1) * 64, K,
              BUF_A64(cur ^ 1), BUF_B64(cur ^ 1), wave);
    const u16* bA = BUF_A64(cur);
    const u16* bB = BUF_B64(cur);
    #pragma unroll
    for (int kk = 0; kk < 2; kk++) {
      int jj = ((kk * 4 + (lane >> 4)) ^ (lane & 7)) * 8;
      bf16x8 af0 = *(const bf16x8*)&bA[arow * 64 + jj];
      bf16x8 af1 = *(const bf16x8*)&bA[(arow + 16) * 64 + jj];
      bf16x8 bf0 = *(const bf16x8*)&bB[brow * 64 + jj];
      bf16x8 bf1 = *(const bf16x8*)&bB[(brow + 16) * 64 + jj];
      acc[0][0] = __builtin_amdgcn_mfma_f32_16x16x32_bf16(af0, bf0, acc[0][0], 0, 0, 0);
      acc[0][1] = __builtin_amdgcn_mfma_f32_16x16x32_bf16(af0, bf1, acc[0][1], 0, 0, 0);
      acc[1][0] = __builtin_amdgcn_mfma_f32_16x16x32_bf16(af1, bf0, acc[1][0], 0, 0, 0);
      acc[1][1] = __builtin_amdgcn_mfma_f32_16x16x32_bf16(af1, bf1, acc[1][1], 0, 0, 0);
    }
    __syncthreads();
  }
}

// ---------------- qkv GEMM with FUSED branch quantization ----------------
// grid (36, 64): bx -> branch = bx/12 (0=q,1=k,2=v), head h = bx%12; m0 = by*64.
__global__ __launch_bounds__(256) void k_gemm_qkv(
    const u16* __restrict__ A, const u16* __restrict__ Bt,
    const float* __restrict__ biasi, const float* __restrict__ qkv_alpha,
    const float* __restrict__ nqw, const float* __restrict__ nqb,
    const float* __restrict__ nkw, const float* __restrict__ nkb,
    const float* __restrict__ scal,
    u16* __restrict__ q2, u16* __restrict__ k2, u16* __restrict__ v2t) {
  const int K = 768;
  __shared__ __align__(16) char smem[32768];
  u16* smem_u16 = (u16*)smem;
  float* xt = (float*)smem;
  int tid = threadIdx.x;
  int lane = tid & 63, wave = tid >> 6;
  int wr = wave >> 1, wc = wave & 1;
  int m0 = blockIdx.y * 64, n0 = blockIdx.x * 64;

  f32x4 acc[2][2];
  #pragma unroll
  for (int mi = 0; mi < 2; mi++)
    #pragma unroll
    for (int ni = 0; ni < 2; ni++) acc[mi][ni] = (f32x4){0.f, 0.f, 0.f, 0.f};

  gemm64(A, Bt, K, m0, n0, smem_u16, lane, wave, acc);

  // ---- phase 1: raw qkv tile (acc + bias) -> LDS [64][65] ----
  int lrow = (lane >> 4) * 4, lcol = lane & 15;
  #pragma unroll
  for (int mi = 0; mi < 2; mi++)
    #pragma unroll
    for (int ni = 0; ni < 2; ni++) {
      int c = wc * 32 + ni * 16 + lcol;
      float bs = biasi[n0 + c];
      #pragma unroll
      for (int rr = 0; rr < 4; rr++) {
        int r = wr * 32 + mi * 16 + lrow + rr;
        xt[r * 65 + c] = acc[mi][ni][rr] + bs;
      }
    }
  __syncthreads();

  // ---- phase 2: branch quantization ----
  int branch = blockIdx.x / 12, h = blockIdx.x % 12;
  int b = m0 >> 10, nb = m0 & 1023;
  if (branch == 2) {
    int d = tid & 63, qr = tid >> 6;
    float av = scal[3];
    float coefv = scal[0] * qkv_alpha[1536 + h * 64 + d];
    u16* dst = v2t + ((size_t)(b * 12 + h) * 64 + d) * 1024 + nb + qr * 16;
    #pragma unroll
    for (int g = 0; g < 2; g++) {
      u16x8 t8;
      #pragma unroll
      for (int j = 0; j < 8; j++) {
        float val = xt[(qr * 16 + g * 8 + j) * 65 + d];
        t8[j] = f2bf(rintf(clip87((val * coefv) / av)));
      }
      *(u16x8*)(dst + g * 8) = t8;
    }
  } else if (tid < 64) {
    int r = tid;
    const float* alph = qkv_alpha + branch * 768 + h * 64;
    const float* wv = branch == 0 ? nqw : nkw;
    const float* bv = branch == 0 ? nqb : nkb;
    float as = branch == 0 ? scal[1] : scal[2];
    float xq[64];
    #pragma unroll
    for (int d = 0; d < 64; d++) xq[d] = xt[r * 65 + d] * alph[d];
    int m = 0, v = 0;
    #pragma unroll
    for (int i = 0; i < 64; i++) {
      int xi = (int)xq[i];
      int dd = xi - m;
      m += (dd * (1024 / (i + 1))) >> 10;   // floor div by 1024
      v += dd * (xi - m);
    }
    float muf = (float)m;
    float den = sqrtf((float)v * 0.015625f) + 1e-5f;
    u16* outp = (branch == 0 ? q2 : k2) + ((size_t)(b * 12 + h) * 1024 + nb + r) * 64;
    #pragma unroll
    for (int g = 0; g < 8; g++) {
      u16x8 t8;
      #pragma unroll
      for (int j = 0; j < 8; j++) {
        int d = g * 8 + j;
        float q1 = (xq[d] - muf) / den;
        float bw = bv[d] / wv[d];
        float t = (q1 + bw) * wv[d] / as;
        t8[j] = f2bf(rintf(clip87(t)));
      }
      *(u16x8*)(outp + g * 8) = t8;
    }
  }
}

// ---------------- proj GEMM ----------------
__global__ __launch_bounds__(256) void k_gemm_proj(
    const u16* __restrict__ A, const u16* __restrict__ Bt,
    float* __restrict__ Cout, const float* __restrict__ palpha,
    const float* __restrict__ pbias, const float* __restrict__ scal) {
  const int K = 768, N = 768;
  __shared__ __align__(16) char smem[32768];
  u16* smem_u16 = (u16*)smem;
  int tid = threadIdx.x;
  int lane = tid & 63, wave = tid >> 6;
  int wr = wave >> 1, wc = wave & 1;
  int m0 = blockIdx.y * 64, n0 = blockIdx.x * 64;

  f32x4 acc[2][2];
  #pragma unroll
  for (int mi = 0; mi < 2; mi++)
    #pragma unroll
    for (int ni = 0; ni < 2; ni++) acc[mi][ni] = (f32x4){0.f, 0.f, 0.f, 0.f};

  gemm64(A, Bt, K, m0, n0, smem_u16, lane, wave, acc);

  int lrow = (lane >> 4) * 4, lcol = lane & 15;
  float ap = scal[5];
  #pragma unroll
  for (int mi = 0; mi < 2; mi++)
    #pragma unroll
    for (int ni = 0; ni < 2; ni++) {
      int col = n0 + wc * 32 + ni * 16 + lcol;
      float pa = palpha[col], pb = pbias[col];
      #pragma unroll
      for (int rr = 0; rr < 4; rr++) {
        int row = m0 + wr * 32 + mi * 16 + lrow + rr;
        Cout[(size_t)row * N + col] = (acc[mi][ni][rr] * pa) * ap + pb;
      }
    }
}

// ---------------- fused attention (reg-staged double-buffer) ----------------
// grid 768 blocks; XCD-swizzled: wg = (flat&7)*96 + flat>>3; qt = wg&15, bh = wg>>4.
__global__ __launch_bounds__(256) void k_attn(
    const u16* __restrict__ q2, const u16* __restrict__ k2,
    const u16* __restrict__ v2t, const float* __restrict__ scal,
    u16* __restrict__ x1q) {
  __shared__ __align__(16) u16 lK[2][64 * 72];
  __shared__ __align__(16) u16 lV[2][64 * 72];
  __shared__ __align__(16) u16 lP[64 * 72];
  __shared__ float rs_lds[64];
  int tid = threadIdx.x, lane = tid & 63, wave = tid >> 6;
  int flat = blockIdx.y * gridDim.x + blockIdx.x;
  int wg = (flat & 7) * 96 + (flat >> 3);     // bijective XCD swizzle (768%8==0)
  int qt = wg & 15, bh = wg >> 4;
  const float escale = scal[6], am = scal[4], am_av = scal[7], apc = scal[5];

  size_t qrow = (size_t)bh * 1024 + qt * 64 + wave * 16 + (lane & 15);
  bf16x8 qf0 = *(const bf16x8*)(q2 + qrow * 64 + (lane >> 4) * 8);
  bf16x8 qf1 = *(const bf16x8*)(q2 + qrow * 64 + 32 + (lane >> 4) * 8);

  const u16* k2b = k2 + (size_t)bh * 1024 * 64;
  const u16* v2b = v2t + (size_t)bh * 64 * 1024;
  int sr = tid >> 2, sc = (tid & 3) * 16;
  int lofs = sr * 72 + sc;

  // ---- pass 1: row sums of attn_exp; K double-buffered via regs ----
  double rsum[4] = {0.0, 0.0, 0.0, 0.0};
  {
    const u16* s0 = k2b + (size_t)sr * 64 + sc;
    u16x8 ka = *(const u16x8*)s0, kb = *(const u16x8*)(s0 + 8);
    *(u16x8*)&lK[0][lofs] = ka;
    *(u16x8*)&lK[0][lofs + 8] = kb;
    __syncthreads();
  }
  int cur = 0;
  for (int kt = 0; kt < 16; kt++) {
    u16x8 ka, kb;
    if (kt < 15) {
      const u16* s1 = k2b + (size_t)((kt + 1) * 64 + sr) * 64 + sc;
      ka = *(const u16x8*)s1; kb = *(const u16x8*)(s1 + 8);
    }
    const u16* lKc = lK[cur];
    float part[4] = {0.f, 0.f, 0.f, 0.f};
    #pragma unroll
    for (int ct = 0; ct < 4; ct++) {
      bf16x8 kf0 = *(const bf16x8*)&lKc[(ct * 16 + (lane & 15)) * 72 + (lane >> 4) * 8];
      bf16x8 kf1 = *(const bf16x8*)&lKc[(ct * 16 + (lane & 15)) * 72 + 32 + (lane >> 4) * 8];
      f32x4 s = {0.f, 0.f, 0.f, 0.f};
      s = __builtin_amdgcn_mfma_f32_16x16x32_bf16(qf0, kf0, s, 0, 0, 0);
      s = __builtin_amdgcn_mfma_f32_16x16x32_bf16(qf1, kf1, s, 0, 0, 0);
      #pragma unroll
      for (int rr = 0; rr < 4; rr++) {
        float e = escale * s[rr];
        float f = floorf(e);
        float pe = ldexpf(1.0f + (e - f), (int)f);
        part[rr] += pe;
      }
    }
    #pragma unroll
    for (int rr = 0; rr < 4; rr++) rsum[rr] += (double)part[rr];
    if (kt < 15) {
      *(u16x8*)&lK[cur ^ 1][lofs] = ka;
      *(u16x8*)&lK[cur ^ 1][lofs + 8] = kb;
    }
    __syncthreads();
    cur ^= 1;
  }
  #pragma unroll
  for (int rr = 0; rr < 4; rr++) {
    double s = rsum[rr];
    s += __shfl_xor(s, 1);
    s += __shfl_xor(s, 2);
    s += __shfl_xor(s, 4);
    s += __shfl_xor(s, 8);
    if ((lane & 15) == 0) rs_lds[wave * 16 + (lane >> 4) * 4 + rr] = (float)s;
  }
  __syncthreads();
  float fac[4];
  #pragma unroll
  for (int rr = 0; rr < 4; rr++)
    fac[rr] = 1.0f / (rs_lds[wave * 16 + (lane >> 4) * 4 + rr] * am);

  // ---- pass 2: recompute S (bitwise identical), quantize attn, PV GEMM ----
  f32x4 accv[4];
  #pragma unroll
  for (int ct = 0; ct < 4; ct++) accv[ct] = (f32x4){0.f, 0.f, 0.f, 0.f};

  {
    const u16* sk = k2b + (size_t)sr * 64 + sc;
    const u16* sv = v2b + (size_t)sr * 1024 + sc;
    u16x8 ka = *(const u16x8*)sk, kb = *(const u16x8*)(sk + 8);
    u16x8 va = *(const u16x8*)sv, vb = *(const u16x8*)(sv + 8);
    *(u16x8*)&lK[0][lofs] = ka;  *(u16x8*)&lK[0][lofs + 8] = kb;
    *(u16x8*)&lV[0][lofs] = va;  *(u16x8*)&lV[0][lofs + 8] = vb;
    __syncthreads();
  }
  cur = 0;
  for (int kt = 0; kt < 16; kt++) {
    u16x8 ka, kb, va, vb;
    if (kt < 15) {
      const u16* sk = k2b + (size_t)((kt + 1) * 64 + sr) * 64 + sc;
      const u16* sv = v2b + (size_t)sr * 1024 + (kt + 1) * 64 + sc;
      ka = *(const u16x8*)sk; kb = *(const u16x8*)(sk + 8);
      va = *(const u16x8*)sv; vb = *(const u16x8*)(sv + 8);
    }
    const u16* lKc = lK[cur];
    #pragma unroll
    for (int ct = 0; ct < 4; ct++) {
      bf16x8 kf0 = *(const bf16x8*)&lKc[(ct * 16 + (lane & 15)) * 72 + (lane >> 4) * 8];
      bf16x8 kf1 = *(const bf16x8*)&lKc[(ct * 16 + (lane & 15)) * 72 + 32 + (lane >> 4) * 8];
      f32x4 s = {0.f, 0.f, 0.f, 0.f};
      s = __builtin_amdgcn_mfma_f32_16x16x32_bf16(qf0, kf0, s, 0, 0, 0);
      s = __builtin_amdgcn_mfma_f32_16x16x32_bf16(qf1, kf1, s, 0, 0, 0);
      #pragma unroll
      for (int rr = 0; rr < 4; rr++) {
        float e = escale * s[rr];
        float f = floorf(e);
        float pe = ldexpf(1.0f + (e - f), (int)f);
        float a2 = rintf(fminf(pe * fac[rr], 7.0f));
        lP[(wave * 16 + (lane >> 4) * 4 + rr) * 72 + ct * 16 + (lane & 15)] = f2bf(a2);
      }
    }
    if (kt < 15) {
      *(u16x8*)&lK[cur ^ 1][lofs] = ka;  *(u16x8*)&lK[cur ^ 1][lofs + 8] = kb;
      *(u16x8*)&lV[cur ^ 1][lofs] = va;  *(u16x8*)&lV[cur ^ 1][lofs + 8] = vb;
    }
    __syncthreads();
    const u16* lVc = lV[cur];
    bf16x8 pf0 = *(const bf16x8*)&lP[(wave * 16 + (lane & 15)) * 72 + (lane >> 4) * 8];
    bf16x8 pf1 = *(const bf16x8*)&lP[(wave * 16 + (lane & 15)) * 72 + 32 + (lane >> 4) * 8];
    #pragma unroll
    for (int ct = 0; ct < 4; ct++) {
      bf16x8 vf0 = *(const bf16x8*)&lVc[(ct * 16 + (lane & 15)) * 72 + (lane >> 4) * 8];
      bf16x8 vf1 = *(const bf16x8*)&lVc[(ct * 16 + (lane & 15)) * 72 + 32 + (lane >> 4) * 8];
      accv[ct] = __builtin_amdgcn_mfma_f32_16x16x32_bf16(pf0, vf0, accv[ct], 0, 0, 0);
      accv[ct] = __builtin_amdgcn_mfma_f32_16x16x32_bf16(pf1, vf1, accv[ct], 0, 0, 0);
    }
    __syncthreads();
    cur ^= 1;
  }

  int b = bh / 12, h = bh % 12;
  #pragma unroll
  for (int ct = 0; ct < 4; ct++)
    #pragma unroll
    for (int rr = 0; rr < 4; rr++) {
      int qr = qt * 64 + wave * 16 + (lane >> 4) * 4 + rr;
      int col = h * 64 + ct * 16 + (lane & 15);
      float t = (accv[ct][rr] * am_av) / apc;
      x1q[((size_t)b * 1024 + qr) * 768 + col] = f2bf(rintf(clip87(t)));
    }
}

extern "C" void kernel_launch(void* const* d_in, const int* in_sizes, int n_in,
                              void* d_out, int out_size, void* d_ws, size_t ws_size,
                              hipStream_t stream) {
  const float* x0             = (const float*)d_in[0];
  const float* qkv_w          = (const float*)d_in[1];
  const float* qkv_b          = (const float*)d_in[2];
  const float* qkv_alpha      = (const float*)d_in[3];
  const float* qkv_act_alpha  = (const float*)d_in[4];
  const float* proj_w         = (const float*)d_in[5];
  const float* proj_b         = (const float*)d_in[6];
  const float* proj_alpha     = (const float*)d_in[7];
  const float* proj_act_alpha = (const float*)d_in[8];
  const float* nqw            = (const float*)d_in[9];
  const float* nqb            = (const float*)d_in[10];
  const float* nkw            = (const float*)d_in[11];
  const float* nkb            = (const float*)d_in[12];
  const float* q_alpha        = (const float*)d_in[13];
  const float* k_alpha        = (const float*)d_in[14];
  const float* v_alpha        = (const float*)d_in[15];
  const float* attn_alpha     = (const float*)d_in[16];
  float* out = (float*)d_out;

  char* ws = (char*)d_ws;
  size_t off = 0;
  auto alloc = [&](size_t bytes) -> void* {
    off = (off + 255) & ~(size_t)255;
    void* p = ws + off;
    off += bytes;
    return p;
  };
  float* scal = (float*)alloc(64);
  u16* wq     = (u16*)alloc((size_t)2304 * 768 * 2);
  u16* wp     = (u16*)alloc((size_t)768 * 768 * 2);
  float* biasi= (float*)alloc((size_t)2304 * 4);
  u16* x0q    = (u16*)alloc((size_t)4096 * 768 * 2);
  u16* q2     = (u16*)alloc((size_t)48 * 1024 * 64 * 2);
  u16* k2     = (u16*)alloc((size_t)48 * 1024 * 64 * 2);
  u16* v2t    = (u16*)alloc((size_t)48 * 1024 * 64 * 2);
  u16* x1q    = (u16*)alloc((size_t)4096 * 768 * 2);

  k_scalars<<<1, 384, 0, stream>>>(qkv_act_alpha, proj_act_alpha, q_alpha, k_alpha,
                                   v_alpha, attn_alpha, scal);

  int totW = 2304 * 768 + 768 * 768 + 2304;
  k_quant_weights<<<(totW + 255) / 256, 256, 0, stream>>>(qkv_w, qkv_alpha, qkv_b,
                                                          proj_w, proj_alpha, scal,
                                                          wq, wp, biasi);

  k_quant_x0<<<(4096 * 768) / (256 * 8), 256, 0, stream>>>(x0, scal, x0q);

  k_gemm_qkv<<<dim3(36, 64), 256, 0, stream>>>(x0q, wq, biasi, qkv_alpha,
                                               nqw, nqb, nkw, nkb, scal,
                                               q2, k2, v2t);

  k_attn<<<dim3(16, 48), 256, 0, stream>>>(q2, k2, v2t, scal, x1q);

  k_gemm_proj<<<dim3(12, 64), 256, 0, stream>>>(x1q, wp, out, proj_alpha, proj_b, scal);
}

// Round 13
// 204.218 us; speedup vs baseline: 1.0653x; 1.0253x over previous
//
#include <hip/hip_runtime.h>

typedef unsigned short u16;
typedef unsigned int u32;
typedef __attribute__((ext_vector_type(8))) u16 u16x8;
typedef __attribute__((ext_vector_type(8))) __bf16 bf16x8;
typedef __attribute__((ext_vector_type(4))) float f32x4;

#define LOG2E_F 1.4426950408889634f

__device__ __forceinline__ u16 f2bf(float f) {
  return (u16)(__float_as_uint(f) >> 16);
}
__device__ __forceinline__ float clip87(float x) {
  return fminf(fmaxf(x, -8.0f), 7.0f);
}
// exact 2^floor(e) * (1 + frac(e)) — matches reference pow2-softmax
__device__ __forceinline__ float pow2exp(float e) {
  float f = floorf(e);
  return ldexpf(1.0f + (e - f), (int)f);
}

// async global->LDS, 16B per lane; lptr must be wave-uniform (HW: lptr + lane*16)
typedef const __attribute__((address_space(1))) u32* gp32;
typedef __attribute__((address_space(3))) u32* lp32;
__device__ __forceinline__ void gl16(const void* g, void* l) {
  __builtin_amdgcn_global_load_lds((gp32)g, (lp32)l, 16, 0, 0);
}

// ---------------- scalar means + derived constants ----------------
// scal: [0]=a_in [1]=aq [2]=ak [3]=av [4]=am [5]=ap [6]=escale [7]=am*av
__global__ void k_scalars(const float* __restrict__ qkv_act_alpha,
                          const float* __restrict__ proj_act_alpha,
                          const float* __restrict__ q_alpha,
                          const float* __restrict__ k_alpha,
                          const float* __restrict__ v_alpha,
                          const float* __restrict__ attn_alpha,
                          float* __restrict__ scal) {
  int tid = threadIdx.x;
  int wave = tid >> 6, lane = tid & 63;
  if (wave < 6) {
    const float* src = nullptr; int n = 0;
    switch (wave) {
      case 0: src = qkv_act_alpha;  n = 768; break;
      case 1: src = q_alpha;        n = 12;  break;
      case 2: src = k_alpha;        n = 12;  break;
      case 3: src = v_alpha;        n = 12;  break;
      case 4: src = attn_alpha;     n = 12;  break;
      case 5: src = proj_act_alpha; n = 768; break;
    }
    double s = 0.0;
    for (int i = lane; i < n; i += 64) s += (double)src[i];
    s += __shfl_xor(s, 1);
    s += __shfl_xor(s, 2);
    s += __shfl_xor(s, 4);
    s += __shfl_xor(s, 8);
    s += __shfl_xor(s, 16);
    s += __shfl_xor(s, 32);
    if (lane == 0) scal[wave] = (float)(s / (double)n);
  }
  __syncthreads();
  if (tid == 0) {
    float aq = scal[1], ak = scal[2];
    float s_ = (0.125f * aq) * ak;   // head_scale * aq * ak
    scal[6] = LOG2E_F * s_;          // escale
    scal[7] = scal[4] * scal[3];     // am * av
  }
}

// ---------------- weight quantization ----------------
__global__ __launch_bounds__(256) void k_quant_weights(
    const float* __restrict__ qkv_w, const float* __restrict__ qkv_alpha,
    const float* __restrict__ qkv_b, const float* __restrict__ proj_w,
    const float* __restrict__ proj_alpha, const float* __restrict__ scal,
    u16* __restrict__ wq, u16* __restrict__ wp, float* __restrict__ biasi) {
  int idx = blockIdx.x * 256 + threadIdx.x;
  const int T1 = 2304 * 768, T2 = 768 * 768;
  if (idx < T1) {
    int o = idx / 768;
    wq[idx] = f2bf(rintf(clip87(qkv_w[idx] / qkv_alpha[o])));
  } else if (idx < T1 + T2) {
    int j = idx - T1;
    int o = j / 768;
    wp[j] = f2bf(rintf(clip87(proj_w[j] / proj_alpha[o])));
  } else if (idx < T1 + T2 + 2304) {
    int o = idx - T1 - T2;
    biasi[o] = truncf((qkv_b[o] / scal[0]) / qkv_alpha[o]);
  }
}

// ---------------- x0 activation quantization ----------------
__global__ __launch_bounds__(256) void k_quant_x0(const float* __restrict__ x0,
                                                  const float* __restrict__ scal,
                                                  u16* __restrict__ x0q) {
  int base = (blockIdx.x * 256 + threadIdx.x) * 8;
  float a = scal[0];
  f32x4 v0 = *(const f32x4*)&x0[base];
  f32x4 v1 = *(const f32x4*)&x0[base + 4];
  u16x8 o;
  #pragma unroll
  for (int j = 0; j < 4; j++) o[j] = f2bf(rintf(clip87(v0[j] / a)));
  #pragma unroll
  for (int j = 0; j < 4; j++) o[4 + j] = f2bf(rintf(clip87(v1[j] / a)));
  *(u16x8*)&x0q[base] = o;
}

// ================= 64x64 GEMM core =================
#define BUF_A64(c) (smem_u16 + (c) * 4096)
#define BUF_B64(c) (smem_u16 + 8192 + (c) * 4096)

__device__ __forceinline__ void stage64(const u16* gAl, const u16* gBl, int K,
                                        u16* bufA, u16* bufB, int w) {
  gl16(gAl, bufA + (w * 16) * 64);
  gl16(gAl + (size_t)8 * K, bufA + (w * 16 + 8) * 64);
  gl16(gBl, bufB + (w * 16) * 64);
  gl16(gBl + (size_t)8 * K, bufB + (w * 16 + 8) * 64);
}

__device__ __forceinline__ void gemm64(const u16* __restrict__ A,
                                       const u16* __restrict__ Bt, int K,
                                       int m0, int n0, u16* smem_u16,
                                       int lane, int wave, f32x4 acc[2][2]) {
  int rsub = lane >> 3;
  int jsrc = (lane & 7) ^ rsub;
  const u16* gAl = A + (size_t)(m0 + wave * 16 + rsub) * K + jsrc * 8;
  const u16* gBl = Bt + (size_t)(n0 + wave * 16 + rsub) * K + jsrc * 8;

  int arow = (wave >> 1) * 32 + (lane & 15);
  int brow = (wave & 1) * 32 + (lane & 15);
  int nsteps = K / 64;

  stage64(gAl, gBl, K, BUF_A64(0), BUF_B64(0), wave);
  __syncthreads();
  for (int t = 0; t < nsteps; t++) {
    int cur = t & 1;
    if (t + 1 < nsteps)
      stage64(gAl + (t + 1) * 64, gBl + (t + 1) * 64, K,
              BUF_A64(cur ^ 1), BUF_B64(cur ^ 1), wave);
    const u16* bA = BUF_A64(cur);
    const u16* bB = BUF_B64(cur);
    #pragma unroll
    for (int kk = 0; kk < 2; kk++) {
      int jj = ((kk * 4 + (lane >> 4)) ^ (lane & 7)) * 8;
      bf16x8 af0 = *(const bf16x8*)&bA[arow * 64 + jj];
      bf16x8 af1 = *(const bf16x8*)&bA[(arow + 16) * 64 + jj];
      bf16x8 bf0 = *(const bf16x8*)&bB[brow * 64 + jj];
      bf16x8 bf1 = *(const bf16x8*)&bB[(brow + 16) * 64 + jj];
      acc[0][0] = __builtin_amdgcn_mfma_f32_16x16x32_bf16(af0, bf0, acc[0][0], 0, 0, 0);
      acc[0][1] = __builtin_amdgcn_mfma_f32_16x16x32_bf16(af0, bf1, acc[0][1], 0, 0, 0);
      acc[1][0] = __builtin_amdgcn_mfma_f32_16x16x32_bf16(af1, bf0, acc[1][0], 0, 0, 0);
      acc[1][1] = __builtin_amdgcn_mfma_f32_16x16x32_bf16(af1, bf1, acc[1][1], 0, 0, 0);
    }
    __syncthreads();
  }
}

// ---------------- qkv GEMM with FUSED branch quantization ----------------
// grid (36, 64): bx -> branch = bx/12 (0=q,1=k,2=v), head h = bx%12; m0 = by*64.
__global__ __launch_bounds__(256) void k_gemm_qkv(
    const u16* __restrict__ A, const u16* __restrict__ Bt,
    const float* __restrict__ biasi, const float* __restrict__ qkv_alpha,
    const float* __restrict__ nqw, const float* __restrict__ nqb,
    const float* __restrict__ nkw, const float* __restrict__ nkb,
    const float* __restrict__ scal,
    u16* __restrict__ q2, u16* __restrict__ k2, u16* __restrict__ v2t) {
  const int K = 768;
  __shared__ __align__(16) char smem[32768];
  u16* smem_u16 = (u16*)smem;
  float* xt = (float*)smem;
  int tid = threadIdx.x;
  int lane = tid & 63, wave = tid >> 6;
  int wr = wave >> 1, wc = wave & 1;
  int m0 = blockIdx.y * 64, n0 = blockIdx.x * 64;

  f32x4 acc[2][2];
  #pragma unroll
  for (int mi = 0; mi < 2; mi++)
    #pragma unroll
    for (int ni = 0; ni < 2; ni++) acc[mi][ni] = (f32x4){0.f, 0.f, 0.f, 0.f};

  gemm64(A, Bt, K, m0, n0, smem_u16, lane, wave, acc);

  // ---- phase 1: raw qkv tile (acc + bias) -> LDS [64][65] ----
  int lrow = (lane >> 4) * 4, lcol = lane & 15;
  #pragma unroll
  for (int mi = 0; mi < 2; mi++)
    #pragma unroll
    for (int ni = 0; ni < 2; ni++) {
      int c = wc * 32 + ni * 16 + lcol;
      float bs = biasi[n0 + c];
      #pragma unroll
      for (int rr = 0; rr < 4; rr++) {
        int r = wr * 32 + mi * 16 + lrow + rr;
        xt[r * 65 + c] = acc[mi][ni][rr] + bs;
      }
    }
  __syncthreads();

  // ---- phase 2: branch quantization ----
  int branch = blockIdx.x / 12, h = blockIdx.x % 12;
  int b = m0 >> 10, nb = m0 & 1023;
  if (branch == 2) {
    int d = tid & 63, qr = tid >> 6;
    float av = scal[3];
    float coefv = scal[0] * qkv_alpha[1536 + h * 64 + d];
    u16* dst = v2t + ((size_t)(b * 12 + h) * 64 + d) * 1024 + nb + qr * 16;
    #pragma unroll
    for (int g = 0; g < 2; g++) {
      u16x8 t8;
      #pragma unroll
      for (int j = 0; j < 8; j++) {
        float val = xt[(qr * 16 + g * 8 + j) * 65 + d];
        t8[j] = f2bf(rintf(clip87((val * coefv) / av)));
      }
      *(u16x8*)(dst + g * 8) = t8;
    }
  } else if (tid < 64) {
    int r = tid;
    const float* alph = qkv_alpha + branch * 768 + h * 64;
    const float* wv = branch == 0 ? nqw : nkw;
    const float* bv = branch == 0 ? nqb : nkb;
    float as = branch == 0 ? scal[1] : scal[2];
    float xq[64];
    #pragma unroll
    for (int d = 0; d < 64; d++) xq[d] = xt[r * 65 + d] * alph[d];
    int m = 0, v = 0;
    #pragma unroll
    for (int i = 0; i < 64; i++) {
      int xi = (int)xq[i];
      int dd = xi - m;
      m += (dd * (1024 / (i + 1))) >> 10;   // floor div by 1024
      v += dd * (xi - m);
    }
    float muf = (float)m;
    float den = sqrtf((float)v * 0.015625f) + 1e-5f;
    u16* outp = (branch == 0 ? q2 : k2) + ((size_t)(b * 12 + h) * 1024 + nb + r) * 64;
    #pragma unroll
    for (int g = 0; g < 8; g++) {
      u16x8 t8;
      #pragma unroll
      for (int j = 0; j < 8; j++) {
        int d = g * 8 + j;
        float q1 = (xq[d] - muf) / den;
        float bw = bv[d] / wv[d];
        float t = (q1 + bw) * wv[d] / as;
        t8[j] = f2bf(rintf(clip87(t)));
      }
      *(u16x8*)(outp + g * 8) = t8;
    }
  }
}

// ---------------- proj GEMM ----------------
__global__ __launch_bounds__(256) void k_gemm_proj(
    const u16* __restrict__ A, const u16* __restrict__ Bt,
    float* __restrict__ Cout, const float* __restrict__ palpha,
    const float* __restrict__ pbias, const float* __restrict__ scal) {
  const int K = 768, N = 768;
  __shared__ __align__(16) char smem[32768];
  u16* smem_u16 = (u16*)smem;
  int tid = threadIdx.x;
  int lane = tid & 63, wave = tid >> 6;
  int wr = wave >> 1, wc = wave & 1;
  int m0 = blockIdx.y * 64, n0 = blockIdx.x * 64;

  f32x4 acc[2][2];
  #pragma unroll
  for (int mi = 0; mi < 2; mi++)
    #pragma unroll
    for (int ni = 0; ni < 2; ni++) acc[mi][ni] = (f32x4){0.f, 0.f, 0.f, 0.f};

  gemm64(A, Bt, K, m0, n0, smem_u16, lane, wave, acc);

  int lrow = (lane >> 4) * 4, lcol = lane & 15;
  float ap = scal[5];
  #pragma unroll
  for (int mi = 0; mi < 2; mi++)
    #pragma unroll
    for (int ni = 0; ni < 2; ni++) {
      int col = n0 + wc * 32 + ni * 16 + lcol;
      float pa = palpha[col], pb = pbias[col];
      #pragma unroll
      for (int rr = 0; rr < 4; rr++) {
        int row = m0 + wr * 32 + mi * 16 + lrow + rr;
        Cout[(size_t)row * N + col] = (acc[mi][ni][rr] * pa) * ap + pb;
      }
    }
}

// ---------------- fused attention (swapped QK^T, lane-local softmax) ----------------
// grid 768 blocks; XCD-swizzled. Per kt: S^T = mfma(K-frag, Q-frag) so each lane
// holds P[q = lane&15][16 k values]; row-sum is lane-local (+2 shfl all-reduce);
// P repack for PV is wave-private LDS (no barrier). S is integer-exact, so
// pass1/pass2 recomputation is bitwise consistent by value, not by schedule.
__global__ __launch_bounds__(256) void k_attn(
    const u16* __restrict__ q2, const u16* __restrict__ k2,
    const u16* __restrict__ v2t, const float* __restrict__ scal,
    u16* __restrict__ x1q) {
  __shared__ __align__(16) u16 lK[2][64 * 72];
  __shared__ __align__(16) u16 lV[2][64 * 72];
  __shared__ __align__(16) u16 lP[4][16 * 72];   // per-wave P tile [16 q][64 k], stride 72
  int tid = threadIdx.x, lane = tid & 63, wave = tid >> 6;
  int flat = blockIdx.y * gridDim.x + blockIdx.x;
  int wg = (flat & 7) * 96 + (flat >> 3);     // bijective XCD swizzle (768%8==0)
  int qt = wg & 15, bh = wg >> 4;
  const float escale = scal[6], am = scal[4], am_av = scal[7], apc = scal[5];
  int q = lane & 15, cc = lane >> 4;

  size_t qrow = (size_t)bh * 1024 + qt * 64 + wave * 16 + q;
  bf16x8 qf0 = *(const bf16x8*)(q2 + qrow * 64 + cc * 8);
  bf16x8 qf1 = *(const bf16x8*)(q2 + qrow * 64 + 32 + cc * 8);

  const u16* k2b = k2 + (size_t)bh * 1024 * 64;
  const u16* v2b = v2t + (size_t)bh * 64 * 1024;
  int sr = tid >> 2, sc = (tid & 3) * 16;
  int lofs = sr * 72 + sc;
  u16* lPw = lP[wave];

  // ---- pass 1: row sums of attn_exp (scalar per lane; K double-buffered) ----
  double rsum = 0.0;
  {
    const u16* s0 = k2b + (size_t)sr * 64 + sc;
    u16x8 ka = *(const u16x8*)s0, kb = *(const u16x8*)(s0 + 8);
    *(u16x8*)&lK[0][lofs] = ka;
    *(u16x8*)&lK[0][lofs + 8] = kb;
    __syncthreads();
  }
  int cur = 0;
  for (int kt = 0; kt < 16; kt++) {
    u16x8 ka, kb;
    if (kt < 15) {
      const u16* s1 = k2b + (size_t)((kt + 1) * 64 + sr) * 64 + sc;
      ka = *(const u16x8*)s1; kb = *(const u16x8*)(s1 + 8);
    }
    const u16* lKc = lK[cur];
    f32x4 st[4];
    #pragma unroll
    for (int ct = 0; ct < 4; ct++) {
      st[ct] = (f32x4){0.f, 0.f, 0.f, 0.f};
      bf16x8 kf0 = *(const bf16x8*)&lKc[(ct * 16 + q) * 72 + cc * 8];
      bf16x8 kf1 = *(const bf16x8*)&lKc[(ct * 16 + q) * 72 + 32 + cc * 8];
      st[ct] = __builtin_amdgcn_mfma_f32_16x16x32_bf16(kf0, qf0, st[ct], 0, 0, 0);
      st[ct] = __builtin_amdgcn_mfma_f32_16x16x32_bf16(kf1, qf1, st[ct], 0, 0, 0);
    }
    float part = 0.f;
    #pragma unroll
    for (int ct = 0; ct < 4; ct++)
      #pragma unroll
      for (int rr = 0; rr < 4; rr++)
        part += pow2exp(escale * st[ct][rr]);
    rsum += (double)part;
    if (kt < 15) {
      *(u16x8*)&lK[cur ^ 1][lofs] = ka;
      *(u16x8*)&lK[cur ^ 1][lofs + 8] = kb;
    }
    __syncthreads();
    cur ^= 1;
  }
  rsum += __shfl_xor(rsum, 16);
  rsum += __shfl_xor(rsum, 32);
  float fac = 1.0f / ((float)rsum * am);

  // ---- pass 2: recompute S (integer-exact), quantize attn, PV GEMM ----
  f32x4 accv[4];
  #pragma unroll
  for (int ct = 0; ct < 4; ct++) accv[ct] = (f32x4){0.f, 0.f, 0.f, 0.f};

  {
    const u16* sk = k2b + (size_t)sr * 64 + sc;
    const u16* sv = v2b + (size_t)sr * 1024 + sc;
    u16x8 ka = *(const u16x8*)sk, kb = *(const u16x8*)(sk + 8);
    u16x8 va = *(const u16x8*)sv, vb = *(const u16x8*)(sv + 8);
    *(u16x8*)&lK[0][lofs] = ka;  *(u16x8*)&lK[0][lofs + 8] = kb;
    *(u16x8*)&lV[0][lofs] = va;  *(u16x8*)&lV[0][lofs + 8] = vb;
    __syncthreads();
  }
  cur = 0;
  for (int kt = 0; kt < 16; kt++) {
    u16x8 ka, kb, va, vb;
    if (kt < 15) {
      const u16* sk = k2b + (size_t)((kt + 1) * 64 + sr) * 64 + sc;
      const u16* sv = v2b + (size_t)sr * 1024 + (kt + 1) * 64 + sc;
      ka = *(const u16x8*)sk; kb = *(const u16x8*)(sk + 8);
      va = *(const u16x8*)sv; vb = *(const u16x8*)(sv + 8);
    }
    const u16* lKc = lK[cur];
    const u16* lVc = lV[cur];
    f32x4 st[4];
    #pragma unroll
    for (int ct = 0; ct < 4; ct++) {
      st[ct] = (f32x4){0.f, 0.f, 0.f, 0.f};
      bf16x8 kf0 = *(const bf16x8*)&lKc[(ct * 16 + q) * 72 + cc * 8];
      bf16x8 kf1 = *(const bf16x8*)&lKc[(ct * 16 + q) * 72 + 32 + cc * 8];
      st[ct] = __builtin_amdgcn_mfma_f32_16x16x32_bf16(kf0, qf0, st[ct], 0, 0, 0);
      st[ct] = __builtin_amdgcn_mfma_f32_16x16x32_bf16(kf1, qf1, st[ct], 0, 0, 0);
    }
    // quantize + pack: lane (q,cc) holds k = 16*ct + 4*cc + rr
    #pragma unroll
    for (int ct = 0; ct < 4; ct++) {
      #pragma unroll
      for (int i = 0; i < 2; i++) {
        float a0 = rintf(fminf(pow2exp(escale * st[ct][2 * i]) * fac, 7.0f));
        float a1 = rintf(fminf(pow2exp(escale * st[ct][2 * i + 1]) * fac, 7.0f));
        u32 w = (u32)f2bf(a0) | ((u32)f2bf(a1) << 16);
        *(u32*)&lPw[q * 72 + 16 * ct + 4 * cc + 2 * i] = w;
      }
    }
    // wave-private RAW: compiler orders via lgkmcnt; no __syncthreads needed
    bf16x8 pf0 = *(const bf16x8*)&lPw[q * 72 + 8 * cc];
    bf16x8 pf1 = *(const bf16x8*)&lPw[q * 72 + 32 + 8 * cc];
    #pragma unroll
    for (int ct = 0; ct < 4; ct++) {
      bf16x8 vf0 = *(const bf16x8*)&lVc[(ct * 16 + q) * 72 + cc * 8];
      bf16x8 vf1 = *(const bf16x8*)&lVc[(ct * 16 + q) * 72 + 32 + cc * 8];
      accv[ct] = __builtin_amdgcn_mfma_f32_16x16x32_bf16(pf0, vf0, accv[ct], 0, 0, 0);
      accv[ct] = __builtin_amdgcn_mfma_f32_16x16x32_bf16(pf1, vf1, accv[ct], 0, 0, 0);
    }
    if (kt < 15) {
      *(u16x8*)&lK[cur ^ 1][lofs] = ka;  *(u16x8*)&lK[cur ^ 1][lofs + 8] = kb;
      *(u16x8*)&lV[cur ^ 1][lofs] = va;  *(u16x8*)&lV[cur ^ 1][lofs + 8] = vb;
    }
    __syncthreads();
    cur ^= 1;
  }

  // epilogue (mapping unchanged): q-row = wave*16 + cc*4 + rr, col = ct*16 + q
  int b = bh / 12, h = bh % 12;
  #pragma unroll
  for (int ct = 0; ct < 4; ct++)
    #pragma unroll
    for (int rr = 0; rr < 4; rr++) {
      int qr = qt * 64 + wave * 16 + cc * 4 + rr;
      int col = h * 64 + ct * 16 + q;
      float t = (accv[ct][rr] * am_av) / apc;
      x1q[((size_t)b * 1024 + qr) * 768 + col] = f2bf(rintf(clip87(t)));
    }
}

extern "C" void kernel_launch(void* const* d_in, const int* in_sizes, int n_in,
                              void* d_out, int out_size, void* d_ws, size_t ws_size,
                              hipStream_t stream) {
  const float* x0             = (const float*)d_in[0];
  const float* qkv_w          = (const float*)d_in[1];
  const float* qkv_b          = (const float*)d_in[2];
  const float* qkv_alpha      = (const float*)d_in[3];
  const float* qkv_act_alpha  = (const float*)d_in[4];
  const float* proj_w         = (const float*)d_in[5];
  const float* proj_b         = (const float*)d_in[6];
  const float* proj_alpha     = (const float*)d_in[7];
  const float* proj_act_alpha = (const float*)d_in[8];
  const float* nqw            = (const float*)d_in[9];
  const float* nqb            = (const float*)d_in[10];
  const float* nkw            = (const float*)d_in[11];
  const float* nkb            = (const float*)d_in[12];
  const float* q_alpha        = (const float*)d_in[13];
  const float* k_alpha        = (const float*)d_in[14];
  const float* v_alpha        = (const float*)d_in[15];
  const float* attn_alpha     = (const float*)d_in[16];
  float* out = (float*)d_out;

  char* ws = (char*)d_ws;
  size_t off = 0;
  auto alloc = [&](size_t bytes) -> void* {
    off = (off + 255) & ~(size_t)255;
    void* p = ws + off;
    off += bytes;
    return p;
  };
  float* scal = (float*)alloc(64);
  u16* wq     = (u16*)alloc((size_t)2304 * 768 * 2);
  u16* wp     = (u16*)alloc((size_t)768 * 768 * 2);
  float* biasi= (float*)alloc((size_t)2304 * 4);
  u16* x0q    = (u16*)alloc((size_t)4096 * 768 * 2);
  u16* q2     = (u16*)alloc((size_t)48 * 1024 * 64 * 2);
  u16* k2     = (u16*)alloc((size_t)48 * 1024 * 64 * 2);
  u16* v2t    = (u16*)alloc((size_t)48 * 1024 * 64 * 2);
  u16* x1q    = (u16*)alloc((size_t)4096 * 768 * 2);

  k_scalars<<<1, 384, 0, stream>>>(qkv_act_alpha, proj_act_alpha, q_alpha, k_alpha,
                                   v_alpha, attn_alpha, scal);

  int totW = 2304 * 768 + 768 * 768 + 2304;
  k_quant_weights<<<(totW + 255) / 256, 256, 0, stream>>>(qkv_w, qkv_alpha, qkv_b,
                                                          proj_w, proj_alpha, scal,
                                                          wq, wp, biasi);

  k_quant_x0<<<(4096 * 768) / (256 * 8), 256, 0, stream>>>(x0, scal, x0q);

  k_gemm_qkv<<<dim3(36, 64), 256, 0, stream>>>(x0q, wq, biasi, qkv_alpha,
                                               nqw, nqb, nkw, nkb, scal,
                                               q2, k2, v2t);

  k_attn<<<dim3(16, 48), 256, 0, stream>>>(q2, k2, v2t, scal, x1q);

  k_gemm_proj<<<dim3(12, 64), 256, 0, stream>>>(x1q, wp, out, proj_alpha, proj_b, scal);
}